// Round 12
// baseline (266.357 us; speedup 1.0000x reference)
//
#include <hip/hip_runtime.h>
#include <hip/hip_bf16.h>
#include <cstdint>
#include <cstddef>

#define AS1 __attribute__((address_space(1)))
#define AS3 __attribute__((address_space(3)))

typedef __attribute__((ext_vector_type(8))) short short8v;
typedef __attribute__((ext_vector_type(4))) float f32x4;
typedef unsigned short u16;

constexpr int kBatch = 16384;
constexpr int kNSp   = 26;
constexpr int kVocab = 50000;
constexpr int kEmb   = 64;
constexpr int kInDim = 1677;   // 26*64 + 13
constexpr int kInPad = 1728;   // padded to x64 (nt=27 odd-safe in gemm256)
constexpr int kDense = 13;
constexpr int kH1 = 1024, kH2 = 512, kH3 = 256;
constexpr float kEps = 1e-5f;

constexpr int kStatsFloats = 2 * (kInPad + kH1 + kH2 + kH3);   // 7040
constexpr int kBfFloats    = kH1 + kH2 + kH3;                  // 1792

// ---------- bf16 helpers (bits held in u16) ----------
__device__ __forceinline__ float b2f(u16 s) {
  unsigned u = ((unsigned)s) << 16;
  union { unsigned u; float f; } c; c.u = u; return c.f;
}
__device__ __forceinline__ u16 f2b(float f) {
  __hip_bfloat16 h = __float2bfloat16(f);   // RNE
  return __builtin_bit_cast(u16, h);
}

// ---------- gather: build raw x0 (bf16, padded) + per-row cross contribution ----------
__global__ void gather_kernel(const int* __restrict__ sparse, const float* __restrict__ dense,
                              const float* __restrict__ emb, const float* __restrict__ w_cross,
                              const float* __restrict__ b_cross, const float* __restrict__ Wp,
                              u16* __restrict__ x0, float* __restrict__ crossc,
                              float* __restrict__ stats) {
  const int b = blockIdx.x;
  const int tid = threadIdx.x;
  if (b == 0) {   // zero stats + bfold accumulators
    for (int i = tid; i < kStatsFloats + kBfFloats; i += 256) stats[i] = 0.f;
  }
  const int idx = sparse[b * kNSp];       // only column 0 is used by the reference
  const float* wc2 = w_cross + 2 * kInDim;
  u16* xrow = x0 + (size_t)b * kInPad;
  float u = 0.f, v = 0.f, w = 0.f;
  for (int q = tid; q < 416; q += 256) {  // 416 = 1664/4
    int p = q * 4;
    const float* src = emb + ((size_t)(p >> 6) * kVocab + idx) * kEmb + (p & 63);
    float4 val = *(const float4*)src;
    float4 wp  = *(const float4*)(Wp + p);
    u += val.x * wc2[p] + val.y * wc2[p + 1] + val.z * wc2[p + 2] + val.w * wc2[p + 3];
    v += val.x * wp.x + val.y * wp.y + val.z * wp.z + val.w * wp.w;
    w += wp.x + wp.y + wp.z + wp.w;
    ushort4 o;
    o.x = f2b(val.x); o.y = f2b(val.y); o.z = f2b(val.z); o.w = f2b(val.w);
    *(ushort4*)(xrow + p) = o;
  }
  int p = 1664 + tid;
  if (p < kInPad) {
    float val = 0.f;
    if (p < kInDim) {
      val = dense[b * kDense + (p - 1664)];
      float wp = Wp[p];
      u += val * wc2[p];
      v += val * wp;
      w += wp;
    }
    xrow[p] = f2b(val);
  }
  #pragma unroll
  for (int off = 32; off; off >>= 1) {
    u += __shfl_down(u, off, 64);
    v += __shfl_down(v, off, 64);
    w += __shfl_down(w, off, 64);
  }
  __shared__ float su[4], sv[4], sw[4];
  int lane = tid & 63, wv = tid >> 6;
  if (lane == 0) { su[wv] = u; sv[wv] = v; sw[wv] = w; }
  __syncthreads();
  if (tid == 0) {
    float uu = su[0] + su[1] + su[2] + su[3];
    float vv = sv[0] + sv[1] + sv[2] + sv[3];
    float ww = sw[0] + sw[1] + sw[2] + sw[3];
    crossc[b] = (1.f + uu) * vv + b_cross[2] * ww;
  }
}

// ---------- per-column sums / sumsq over batch (x0 only) ----------
__global__ void colstats_kernel(const u16* __restrict__ X, int ld, int rpb,
                                float* __restrict__ sum, float* __restrict__ sq) {
  int c  = threadIdx.x & 63;
  int rg = threadIdx.x >> 6;   // 0..3
  int col = blockIdx.x * 64 + c;
  int r0  = blockIdx.y * rpb;
  float s = 0.f, s2 = 0.f;
  for (int r = r0 + rg; r < r0 + rpb; r += 4) {
    float v = b2f(X[(size_t)r * ld + col]);
    s += v; s2 += v * v;
  }
  __shared__ float sh[8][64];
  sh[rg][c] = s; sh[rg + 4][c] = s2;
  __syncthreads();
  if (rg == 0) atomicAdd(&sum[col], sh[0][c] + sh[1][c] + sh[2][c] + sh[3][c]);
  else if (rg == 1) atomicAdd(&sq[col], sh[4][c] + sh[5][c] + sh[6][c] + sh[7][c]);
}

// ---------- fused layer-boundary: BN-affine from stats + transpose + scale-fold
//            + wave-reduced bias-fold. ----------
__global__ void fold_kernel(const float* __restrict__ W, const float* __restrict__ sum,
                            const float* __restrict__ sq, const float* __restrict__ g,
                            const float* __restrict__ bb, float invM,
                            u16* __restrict__ Wt, float* __restrict__ bfold,
                            int K, int N, int Kp) {
  __shared__ float t[64][65];
  int kb = blockIdx.x * 64;
  int nb = blockIdx.y * 64;
  int c  = threadIdx.x & 63;
  int r0 = threadIdx.x >> 6;   // 0..3
  #pragma unroll
  for (int rr = 0; rr < 64; rr += 4) {
    int k = kb + rr + r0;
    t[rr + r0][c] = (k < K) ? W[(size_t)k * N + nb + c] : 0.f;
  }
  __syncthreads();
  int k = kb + c;
  float a = 0.f, cc = 0.f;
  if (k < K) {
    float mu  = sum[k] * invM;
    float var = sq[k] * invM - mu * mu;
    a  = g[k] * rsqrtf(var + kEps);
    cc = bb[k] - a * mu;
  }
  #pragma unroll
  for (int rr = 0; rr < 64; rr += 4) {
    int n = nb + rr + r0;
    float w = t[c][rr + r0];
    Wt[(size_t)n * Kp + k] = f2b(w * a);
    float part = cc * w;
    #pragma unroll
    for (int off = 32; off; off >>= 1) part += __shfl_xor(part, off, 64);
    if (c == 0) atomicAdd(&bfold[n], part);
  }
}

// ---------- 128x128 MFMA GEMM (verified m97-structure) for layer 3 ----------
__global__ __launch_bounds__(256) void gemm_kernel(
    const u16* __restrict__ A, const u16* __restrict__ Bt,
    const float* __restrict__ bias, const float* __restrict__ bfold,
    u16* __restrict__ Z, float* __restrict__ sum, float* __restrict__ sq,
    int M, int N, int Kp) {
  __shared__ char lds[32768];
  char* ldsA = lds;
  char* ldsB = lds + 16384;
  const int tid  = threadIdx.x;
  const int lane = tid & 63;
  const int wv   = tid >> 6;
  const int wr = wv >> 1, wc = wv & 1;
  const int r16 = lane & 15, kg = lane >> 4;

  const int L   = blockIdx.y * gridDim.x + blockIdx.x;
  const int xcd = L & 7;
  const int j   = L >> 3;
  const int mb  = xcd * 16 + (j & 15);
  const int nb  = j >> 4;
  const int m0 = mb * 128;
  const int n0 = nb * 128;
  const int ldb = Kp * 2;

  const char* gA = (const char*)A + (size_t)m0 * ldb;
  const char* gB = (const char*)Bt + (size_t)n0 * ldb;

  const char* srcA[4]; const char* srcB[4]; int dst[4];
  #pragma unroll
  for (int rr = 0; rr < 4; ++rr) {
    int lb  = (rr * 256 + tid) * 16;
    int row = lb >> 7;
    int kb  = lb & 127;
    int kbs = kb ^ ((row & 7) << 4);
    dst[rr]  = lb;
    srcA[rr] = gA + (size_t)row * ldb + kbs;
    srcB[rr] = gB + (size_t)row * ldb + kbs;
  }

  f32x4 acc[4][4];
  #pragma unroll
  for (int m = 0; m < 4; ++m)
    #pragma unroll
    for (int n = 0; n < 4; ++n) acc[m][n] = (f32x4){0.f, 0.f, 0.f, 0.f};

  for (int k0 = 0; k0 < Kp; k0 += 64) {
    __syncthreads();
    #pragma unroll
    for (int rr = 0; rr < 4; ++rr)
      __builtin_amdgcn_global_load_lds((const AS1 unsigned*)(srcA[rr] + k0 * 2),
                                       (AS3 unsigned*)(ldsA + dst[rr]), 16, 0, 0);
    #pragma unroll
    for (int rr = 0; rr < 4; ++rr)
      __builtin_amdgcn_global_load_lds((const AS1 unsigned*)(srcB[rr] + k0 * 2),
                                       (AS3 unsigned*)(ldsB + dst[rr]), 16, 0, 0);
    asm volatile("s_waitcnt vmcnt(0)" ::: "memory");
    __syncthreads();
    #pragma unroll
    for (int kk = 0; kk < 2; ++kk) {
      short8v av[4], bv[4];
      #pragma unroll
      for (int m = 0; m < 4; ++m) {
        int row = wr * 64 + m * 16 + r16;
        int kb  = (kk * 64 + kg * 16) ^ ((row & 7) << 4);
        av[m] = *(const short8v*)(ldsA + row * 128 + kb);
      }
      #pragma unroll
      for (int n = 0; n < 4; ++n) {
        int row = wc * 64 + n * 16 + r16;
        int kb  = (kk * 64 + kg * 16) ^ ((row & 7) << 4);
        bv[n] = *(const short8v*)(ldsB + row * 128 + kb);
      }
      #pragma unroll
      for (int m = 0; m < 4; ++m)
        #pragma unroll
        for (int n = 0; n < 4; ++n)
          acc[m][n] = __builtin_amdgcn_mfma_f32_16x16x32_bf16(av[m], bv[n], acc[m][n], 0, 0, 0);
    }
  }
  #pragma unroll
  for (int n = 0; n < 4; ++n) {
    int col = n0 + wc * 64 + n * 16 + r16;
    float bs = bias[col] + bfold[col];
    float ps = 0.f, pq = 0.f;
    #pragma unroll
    for (int m = 0; m < 4; ++m) {
      int rbase = m0 + wr * 64 + m * 16 + kg * 4;
      #pragma unroll
      for (int j2 = 0; j2 < 4; ++j2) {
        float val = acc[m][n][j2] + bs;
        Z[(size_t)(rbase + j2) * N + col] = f2b(val);
        ps += val; pq += val * val;
      }
    }
    ps += __shfl_xor(ps, 16, 64); ps += __shfl_xor(ps, 32, 64);
    pq += __shfl_xor(pq, 16, 64); pq += __shfl_xor(pq, 32, 64);
    if (lane < 16) {
      atomicAdd(&sum[col], ps);
      atomicAdd(&sq[col],  pq);
    }
  }
}

// ===== shared barrier macros for pipelined kernels =====
#define BAR_VMN(N)                                                              \
  {                                                                             \
    asm volatile("s_waitcnt vmcnt(" #N ")" ::: "memory");                       \
    __builtin_amdgcn_sched_barrier(0);                                          \
    __builtin_amdgcn_s_barrier();                                               \
    __builtin_amdgcn_sched_barrier(0);                                          \
  }
#define BAR_NOVM()                                                              \
  {                                                                             \
    __builtin_amdgcn_sched_barrier(0);                                          \
    __builtin_amdgcn_s_barrier();                                               \
    __builtin_amdgcn_sched_barrier(0);                                          \
  }

// ---------- 256x256 8-wave 4-phase/K-tile pipelined GEMM (layer 1) ----------
#define STAGE(OP, H, TILE)                                                      \
  {                                                                             \
    const char* sb = ((OP) ? gB : gA) + (size_t)((H) * 128) * ldb               \
                     + (size_t)(TILE) * 128 + srcoff;                           \
    char* db = lds + (((TILE) & 1) << 16) + ((OP) << 15) + ((H) << 14) + tid * 16; \
    __builtin_amdgcn_global_load_lds((const AS1 unsigned*)sb,                   \
                                     (AS3 unsigned*)db, 16, 0, 0);              \
    __builtin_amdgcn_global_load_lds((const AS1 unsigned*)(sb + 64 * (size_t)ldb), \
                                     (AS3 unsigned*)(db + 8192), 16, 0, 0);     \
  }

#define PHASE(T, MH, NH)                                                        \
  {                                                                             \
    char* la  = lds + (((T) & 1) << 16);                                        \
    char* lbp = la + 32768;                                                     \
    short8v av[4][2], bv[2][2];                                                 \
    _Pragma("unroll")                                                           \
    for (int fm = 0; fm < 4; ++fm) {                                            \
      int row = (MH) * 128 + wr * 64 + fm * 16 + r16;                           \
      _Pragma("unroll")                                                         \
      for (int kk = 0; kk < 2; ++kk) {                                          \
        int kb = (kk * 64 + kg * 16) ^ ((row & 7) << 4);                        \
        av[fm][kk] = *(const short8v*)(la + row * 128 + kb);                    \
      }                                                                         \
    }                                                                           \
    _Pragma("unroll")                                                           \
    for (int fn = 0; fn < 2; ++fn) {                                            \
      int row = (NH) * 128 + wc * 32 + fn * 16 + r16;                           \
      _Pragma("unroll")                                                         \
      for (int kk = 0; kk < 2; ++kk) {                                          \
        int kb = (kk * 64 + kg * 16) ^ ((row & 7) << 4);                        \
        bv[fn][kk] = *(const short8v*)(lbp + row * 128 + kb);                   \
      }                                                                         \
    }                                                                           \
    __builtin_amdgcn_s_setprio(1);                                              \
    _Pragma("unroll")                                                           \
    for (int fm = 0; fm < 4; ++fm)                                              \
      _Pragma("unroll")                                                         \
      for (int fn = 0; fn < 2; ++fn)                                            \
        _Pragma("unroll")                                                       \
        for (int kk = 0; kk < 2; ++kk)                                          \
          acc[(MH) * 4 + fm][(NH) * 2 + fn] =                                   \
              __builtin_amdgcn_mfma_f32_16x16x32_bf16(                          \
                  av[fm][kk], bv[fn][kk],                                       \
                  acc[(MH) * 4 + fm][(NH) * 2 + fn], 0, 0, 0);                  \
    __builtin_amdgcn_s_setprio(0);                                              \
  }

__global__ __launch_bounds__(512, 2) void gemm256_kernel(
    const u16* __restrict__ A, const u16* __restrict__ Bt,
    const float* __restrict__ bias, const float* __restrict__ bfold,
    u16* __restrict__ Z, float* __restrict__ sum, float* __restrict__ sq,
    int M, int N, int Kp) {
  __shared__ char lds[131072];
  const int tid  = threadIdx.x;
  const int lane = tid & 63;
  const int wid  = tid >> 6;           // 0..7
  const int wr = wid >> 2, wc = wid & 3;  // 2M x 4N waves
  const int r16 = lane & 15, kg = lane >> 4;

  const int nmb = M >> 8;
  const int cpx = nmb >> 3;
  const int L   = blockIdx.x;
  const int xcd = L & 7;
  const int jj  = L >> 3;
  const int mb  = xcd * cpx + (jj % cpx);
  const int nb  = jj / cpx;
  const int m0  = mb * 256;
  const int n0  = nb * 256;
  const int ldb = Kp * 2;
  const int nt  = Kp >> 6;

  const char* gA = (const char*)A + (size_t)m0 * ldb;
  const char* gB = (const char*)Bt + (size_t)n0 * ldb;
  const int row0 = tid >> 3;
  const int kbs  = ((tid & 7) * 16) ^ ((row0 & 7) << 4);
  const size_t srcoff = (size_t)row0 * ldb + kbs;

  f32x4 acc[8][4];
  #pragma unroll
  for (int m = 0; m < 8; ++m)
    #pragma unroll
    for (int n = 0; n < 4; ++n) acc[m][n] = (f32x4){0.f, 0.f, 0.f, 0.f};

  STAGE(0, 0, 0); STAGE(1, 0, 0); STAGE(1, 1, 0); STAGE(0, 1, 0);
  STAGE(0, 0, 1); STAGE(1, 0, 1);
  BAR_VMN(8);

  const int Tmain = nt - 2;
  for (int T = 0; T < Tmain; ++T) {
    STAGE(1, 1, T + 1);
    PHASE(T, 0, 0);
    BAR_VMN(8);
    STAGE(0, 1, T + 1);
    PHASE(T, 0, 1);
    BAR_VMN(8);
    if (T + 2 < nt) STAGE(0, 0, T + 2);
    PHASE(T, 1, 0);
    BAR_NOVM();
    if (T + 2 < nt) STAGE(1, 0, T + 2);
    PHASE(T, 1, 1);
    BAR_VMN(8);
  }
  for (int T = Tmain; T < nt; ++T) {
    if (T + 1 < nt) STAGE(1, 1, T + 1);
    PHASE(T, 0, 0);
    BAR_VMN(0);
    if (T + 1 < nt) STAGE(0, 1, T + 1);
    PHASE(T, 0, 1);
    BAR_VMN(0);
    PHASE(T, 1, 0);
    BAR_NOVM();
    PHASE(T, 1, 1);
    BAR_VMN(0);
  }

  #pragma unroll
  for (int nh = 0; nh < 2; ++nh)
    #pragma unroll
    for (int fn = 0; fn < 2; ++fn) {
      int col = n0 + nh * 128 + wc * 32 + fn * 16 + r16;
      float bs = bias[col] + bfold[col];
      float ps = 0.f, pq = 0.f;
      #pragma unroll
      for (int mh = 0; mh < 2; ++mh)
        #pragma unroll
        for (int fm = 0; fm < 4; ++fm) {
          int rbase = m0 + mh * 128 + wr * 64 + fm * 16 + kg * 4;
          #pragma unroll
          for (int j2 = 0; j2 < 4; ++j2) {
            float val = acc[mh * 4 + fm][nh * 2 + fn][j2] + bs;
            Z[(size_t)(rbase + j2) * N + col] = f2b(val);
            ps += val; pq += val * val;
          }
        }
      ps += __shfl_xor(ps, 16, 64); ps += __shfl_xor(ps, 32, 64);
      pq += __shfl_xor(pq, 16, 64); pq += __shfl_xor(pq, 32, 64);
      if (lane < 16) {
        atomicAdd(&sum[col], ps);
        atomicAdd(&sq[col],  pq);
      }
    }
}

// ---------- 256x128-tile 8-wave 2-phase/K-tile pipelined GEMM (layer 2) ----------
#define STAGE2A(H, TILE)                                                        \
  {                                                                             \
    const char* sb = gA + (size_t)((H) * 128) * ldb + (size_t)(TILE) * 128 + srcoff; \
    char* db = lds + (((TILE) & 1) << 15) + ((H) << 14) + tid * 16;             \
    __builtin_amdgcn_global_load_lds((const AS1 unsigned*)sb,                   \
                                     (AS3 unsigned*)db, 16, 0, 0);              \
    __builtin_amdgcn_global_load_lds((const AS1 unsigned*)(sb + 64 * (size_t)ldb), \
                                     (AS3 unsigned*)(db + 8192), 16, 0, 0);     \
  }
#define STAGE2B(TILE)                                                           \
  {                                                                             \
    const char* sb = gB + (size_t)(TILE) * 128 + srcoff;                        \
    char* db = lds + 65536 + (((TILE) & 1) << 14) + tid * 16;                   \
    __builtin_amdgcn_global_load_lds((const AS1 unsigned*)sb,                   \
                                     (AS3 unsigned*)db, 16, 0, 0);              \
    __builtin_amdgcn_global_load_lds((const AS1 unsigned*)(sb + 64 * (size_t)ldb), \
                                     (AS3 unsigned*)(db + 8192), 16, 0, 0);     \
  }

#define PHASE2(T, MH)                                                           \
  {                                                                             \
    char* la  = lds + (((T) & 1) << 15) + ((MH) << 14);                         \
    char* lbp = lds + 65536 + (((T) & 1) << 14);                                \
    short8v av[4][2], bv[2][2];                                                 \
    _Pragma("unroll")                                                           \
    for (int fm = 0; fm < 4; ++fm) {                                            \
      int row = wr * 64 + fm * 16 + r16;                                        \
      _Pragma("unroll")                                                         \
      for (int kk = 0; kk < 2; ++kk) {                                          \
        int kb = (kk * 64 + kg * 16) ^ ((row & 7) << 4);                        \
        av[fm][kk] = *(const short8v*)(la + row * 128 + kb);                    \
      }                                                                         \
    }                                                                           \
    _Pragma("unroll")                                                           \
    for (int fn = 0; fn < 2; ++fn) {                                            \
      int row = wc * 32 + fn * 16 + r16;                                        \
      _Pragma("unroll")                                                         \
      for (int kk = 0; kk < 2; ++kk) {                                          \
        int kb = (kk * 64 + kg * 16) ^ ((row & 7) << 4);                        \
        bv[fn][kk] = *(const short8v*)(lbp + row * 128 + kb);                   \
      }                                                                         \
    }                                                                           \
    __builtin_amdgcn_s_setprio(1);                                              \
    _Pragma("unroll")                                                           \
    for (int fm = 0; fm < 4; ++fm)                                              \
      _Pragma("unroll")                                                         \
      for (int fn = 0; fn < 2; ++fn)                                            \
        _Pragma("unroll")                                                       \
        for (int kk = 0; kk < 2; ++kk)                                          \
          acc[(MH) * 4 + fm][fn] =                                              \
              __builtin_amdgcn_mfma_f32_16x16x32_bf16(                          \
                  av[fm][kk], bv[fn][kk], acc[(MH) * 4 + fm][fn], 0, 0, 0);     \
    __builtin_amdgcn_s_setprio(0);                                              \
  }

__global__ __launch_bounds__(512, 2) void gemm256x128_kernel(
    const u16* __restrict__ A, const u16* __restrict__ Bt,
    const float* __restrict__ bias, const float* __restrict__ bfold,
    u16* __restrict__ Z, float* __restrict__ sum, float* __restrict__ sq,
    int M, int N, int Kp) {
  __shared__ char lds[98304];
  const int tid  = threadIdx.x;
  const int lane = tid & 63;
  const int wid  = tid >> 6;              // 0..7
  const int wr = wid >> 2, wc = wid & 3;  // 2M x 4N
  const int r16 = lane & 15, kg = lane >> 4;

  const int nmb = M >> 8;                 // 64
  const int cpx = nmb >> 3;               // 8
  const int L   = blockIdx.x;
  const int xcd = L & 7;
  const int jj  = L >> 3;
  const int mb  = xcd * cpx + (jj % cpx);
  const int nb  = jj / cpx;
  const int m0  = mb * 256;
  const int n0  = nb * 128;
  const int ldb = Kp * 2;
  const int nt  = Kp >> 6;

  const char* gA = (const char*)A + (size_t)m0 * ldb;
  const char* gB = (const char*)Bt + (size_t)n0 * ldb;
  const int row0 = tid >> 3;
  const int kbs  = ((tid & 7) * 16) ^ ((row0 & 7) << 4);
  const size_t srcoff = (size_t)row0 * ldb + kbs;

  f32x4 acc[8][2];
  #pragma unroll
  for (int m = 0; m < 8; ++m)
    #pragma unroll
    for (int n = 0; n < 2; ++n) acc[m][n] = (f32x4){0.f, 0.f, 0.f, 0.f};

  STAGE2A(0, 0); STAGE2B(0); STAGE2A(1, 0);

  const int Tmain = nt - 1;
  for (int T = 0; T < Tmain; ++T) {
    STAGE2A(0, T + 1); STAGE2B(T + 1);   // 4 inst
    BAR_VMN(6);                          // proves A0,B(T)
    PHASE2(T, 0);
    STAGE2A(1, T + 1);                   // 2 inst
    BAR_VMN(6);                          // proves A1(T)
    PHASE2(T, 1);
    BAR_NOVM();
  }
  BAR_VMN(2);
  PHASE2(nt - 1, 0);
  BAR_VMN(0);
  PHASE2(nt - 1, 1);

  #pragma unroll
  for (int fn = 0; fn < 2; ++fn) {
    int col = n0 + wc * 32 + fn * 16 + r16;
    float bs = bias[col] + bfold[col];
    float ps = 0.f, pq = 0.f;
    #pragma unroll
    for (int mh = 0; mh < 2; ++mh)
      #pragma unroll
      for (int fm = 0; fm < 4; ++fm) {
        int rbase = m0 + mh * 128 + wr * 64 + fm * 16 + kg * 4;
        #pragma unroll
        for (int j2 = 0; j2 < 4; ++j2) {
          float val = acc[mh * 4 + fm][fn][j2] + bs;
          Z[(size_t)(rbase + j2) * N + col] = f2b(val);
          ps += val; pq += val * val;
        }
      }
    ps += __shfl_xor(ps, 16, 64); ps += __shfl_xor(ps, 32, 64);
    pq += __shfl_xor(pq, 16, 64); pq += __shfl_xor(pq, 32, 64);
    if (lane < 16) {
      atomicAdd(&sum[col], ps);
      atomicAdd(&sq[col],  pq);
    }
  }
}

// ---------- final: BN3 inline from stats + concat-dot + sigmoid (float32 out) ----------
__global__ void final_kernel(const u16* __restrict__ z3, const float* __restrict__ sum3,
                             const float* __restrict__ sq3, const float* __restrict__ g3,
                             const float* __restrict__ b3, float invM,
                             const float* __restrict__ Wp, const float* __restrict__ bp,
                             const float* __restrict__ crossc, float* __restrict__ out) {
  int wv = threadIdx.x >> 6, lane = threadIdx.x & 63;
  int b = blockIdx.x * 4 + wv;
  const float* wph = Wp + kInDim;
  float s = 0.f;
  #pragma unroll
  for (int k = lane; k < kH3; k += 64) {
    float mu  = sum3[k] * invM;
    float var = sq3[k] * invM - mu * mu;
    float a   = g3[k] * rsqrtf(var + kEps);
    float cc  = b3[k] - a * mu;
    float h = a * b2f(z3[(size_t)b * kH3 + k]) + cc;
    s += h * wph[k];
  }
  #pragma unroll
  for (int off = 32; off; off >>= 1) s += __shfl_down(s, off, 64);
  if (lane == 0) {
    float logit = s + crossc[b] + bp[0];
    out[b] = 1.f / (1.f + expf(-logit));
  }
}

// ---------- workspace layout ----------
constexpr size_t OFF_X0    = 0;                                   // 16384*1728*2
constexpr size_t OFF_Z1    = OFF_X0 + (size_t)kBatch * kInPad * 2;
constexpr size_t OFF_Z2    = OFF_Z1 + (size_t)kBatch * kH1 * 2;
constexpr size_t OFF_Z3    = OFF_Z2 + (size_t)kBatch * kH2 * 2;
constexpr size_t OFF_W1T   = OFF_Z3 + (size_t)kBatch * kH3 * 2;
constexpr size_t OFF_W2T   = OFF_W1T + (size_t)kH1 * kInPad * 2;
constexpr size_t OFF_W3T   = OFF_W2T + (size_t)kH2 * kH1 * 2;
constexpr size_t OFF_CROSS = OFF_W3T + (size_t)kH3 * kH2 * 2;
constexpr size_t OFF_STATS = OFF_CROSS + (size_t)kBatch * 4;
constexpr size_t OFF_BF    = OFF_STATS + (size_t)kStatsFloats * 4;
constexpr size_t OFF_DUMMY = OFF_BF + (size_t)kBfFloats * 4;      // write-only probe stats
// total ~115 MB

extern "C" void kernel_launch(void* const* d_in, const int* in_sizes, int n_in,
                              void* d_out, int out_size, void* d_ws, size_t ws_size,
                              hipStream_t stream) {
  const int*   sparse  = (const int*)d_in[0];
  const float* dense   = (const float*)d_in[1];
  const float* emb     = (const float*)d_in[2];
  const float* w_cross = (const float*)d_in[3];
  const float* b_cross = (const float*)d_in[4];
  const float* bn0_g = (const float*)d_in[5],  *bn0_b = (const float*)d_in[6];
  const float* W1    = (const float*)d_in[7],  *bias1 = (const float*)d_in[8];
  const float* bn1_g = (const float*)d_in[9],  *bn1_b = (const float*)d_in[10];
  const float* W2    = (const float*)d_in[11], *bias2 = (const float*)d_in[12];
  const float* bn2_g = (const float*)d_in[13], *bn2_b = (const float*)d_in[14];
  const float* W3    = (const float*)d_in[15], *bias3 = (const float*)d_in[16];
  const float* bn3_g = (const float*)d_in[17], *bn3_b = (const float*)d_in[18];
  const float* Wp    = (const float*)d_in[19], *bp    = (const float*)d_in[20];

  char* ws = (char*)d_ws;
  u16* x0  = (u16*)(ws + OFF_X0);
  u16* z1  = (u16*)(ws + OFF_Z1);
  u16* z2  = (u16*)(ws + OFF_Z2);
  u16* z3  = (u16*)(ws + OFF_Z3);
  u16* W1t = (u16*)(ws + OFF_W1T);
  u16* W2t = (u16*)(ws + OFF_W2T);
  u16* W3t = (u16*)(ws + OFF_W3T);
  float* crossc = (float*)(ws + OFF_CROSS);
  float* stats  = (float*)(ws + OFF_STATS);
  float* sum0 = stats,            *sq0 = stats + kInPad;
  float* sum1 = sq0 + kInPad,     *sq1 = sum1 + kH1;
  float* sum2 = sq1 + kH1,        *sq2 = sum2 + kH2;
  float* sum3 = sq2 + kH2,        *sq3 = sum3 + kH3;
  float* bfold = (float*)(ws + OFF_BF);
  float* b1f = bfold, *b2f = b1f + kH1, *b3f = b2f + kH2;
  float* dumS = (float*)(ws + OFF_DUMMY);          // write-only, never read
  float* dumQ = dumS + kH1;
  float* out = (float*)d_out;

  const float invM = 1.f / (float)kBatch;

  // gather also zeroes stats (block 0) and computes per-block sum(Wp) locally
  gather_kernel<<<kBatch, 256, 0, stream>>>(sparse, dense, emb, w_cross, b_cross, Wp,
                                            x0, crossc, stats);

  // BN0 stats -> fold into W1/bias1
  colstats_kernel<<<dim3(kInPad / 64, 32), 256, 0, stream>>>(x0, kInPad, kBatch / 32, sum0, sq0);
  fold_kernel<<<dim3(kInPad / 64, kH1 / 64), 256, 0, stream>>>(
      W1, sum0, sq0, bn0_g, bn0_b, invM, W1t, b1f, kInDim, kH1, kInPad);

  // layer 1: 256x256 pipelined GEMM (stats fused)
  gemm256_kernel<<<(kBatch / 256) * (kH1 / 256), 512, 0, stream>>>(
      x0, W1t, bias1, b1f, z1, sum1, sq1, kBatch, kH1, kInPad);
  fold_kernel<<<dim3(kH1 / 64, kH2 / 64), 256, 0, stream>>>(
      W2, sum1, sq1, bn1_g, bn1_b, invM, W2t, b2f, kH1, kH2, kH1);

  // layer 2: 256x128 pipelined GEMM (stats fused)
  gemm256x128_kernel<<<(kBatch / 256) * (kH2 / 128), 512, 0, stream>>>(
      z1, W2t, bias2, b2f, z2, sum2, sq2, kBatch, kH2, kH1);
  // === MEASUREMENT PROBE (round 12a): duplicate GEMM2, stats -> dummy.    ===
  gemm256x128_kernel<<<(kBatch / 256) * (kH2 / 128), 512, 0, stream>>>(
      z1, W2t, bias2, b2f, z2, dumS, dumQ, kBatch, kH2, kH1);
  fold_kernel<<<dim3(kH2 / 64, kH3 / 64), 256, 0, stream>>>(
      W3, sum2, sq2, bn2_g, bn2_b, invM, W3t, b3f, kH2, kH3, kH2);

  // layer 3 (BN3 inline in final)
  gemm_kernel<<<dim3(kH3 / 128, kBatch / 128), 256, 0, stream>>>(
      z2, W3t, bias3, b3f, z3, sum3, sq3, kBatch, kH3, kH2);
  // === MEASUREMENT PROBE (round 12b): duplicate GEMM3, stats -> dummy.    ===
  gemm_kernel<<<dim3(kH3 / 128, kBatch / 128), 256, 0, stream>>>(
      z2, W3t, bias3, b3f, z3, dumS, dumQ, kBatch, kH3, kH2);

  final_kernel<<<kBatch / 4, 256, 0, stream>>>(z3, sum3, sq3, bn3_g, bn3_b, invM,
                                               Wp, bp, crossc, out);
}

// Round 13
// 197.845 us; speedup vs baseline: 1.3463x; 1.3463x over previous
//
#include <hip/hip_runtime.h>
#include <hip/hip_bf16.h>
#include <cstdint>
#include <cstddef>

#define AS1 __attribute__((address_space(1)))
#define AS3 __attribute__((address_space(3)))

typedef __attribute__((ext_vector_type(8))) short short8v;
typedef __attribute__((ext_vector_type(4))) float f32x4;
typedef unsigned short u16;

constexpr int kBatch = 16384;
constexpr int kNSp   = 26;
constexpr int kVocab = 50000;
constexpr int kEmb   = 64;
constexpr int kInDim = 1677;   // 26*64 + 13
constexpr int kInPad = 1728;   // padded to x64 (nt=27 odd-safe in gemm256)
constexpr int kDense = 13;
constexpr int kH1 = 1024, kH2 = 512, kH3 = 256;
constexpr float kEps = 1e-5f;

constexpr int kStatsFloats = 2 * (kInPad + kH1 + kH2 + kH3);   // 7040
constexpr int kBfFloats    = kH1 + kH2 + kH3;                  // 1792

// ---------- bf16 helpers (bits held in u16) ----------
__device__ __forceinline__ float b2f(u16 s) {
  unsigned u = ((unsigned)s) << 16;
  union { unsigned u; float f; } c; c.u = u; return c.f;
}
__device__ __forceinline__ u16 f2b(float f) {
  __hip_bfloat16 h = __float2bfloat16(f);   // RNE
  return __builtin_bit_cast(u16, h);
}

// ---------- gather: build raw x0 (bf16, padded) + per-row cross contribution ----------
__global__ void gather_kernel(const int* __restrict__ sparse, const float* __restrict__ dense,
                              const float* __restrict__ emb, const float* __restrict__ w_cross,
                              const float* __restrict__ b_cross, const float* __restrict__ Wp,
                              u16* __restrict__ x0, float* __restrict__ crossc,
                              float* __restrict__ stats) {
  const int b = blockIdx.x;
  const int tid = threadIdx.x;
  if (b == 0) {   // zero stats + bfold accumulators
    for (int i = tid; i < kStatsFloats + kBfFloats; i += 256) stats[i] = 0.f;
  }
  const int idx = sparse[b * kNSp];       // only column 0 is used by the reference
  const float* wc2 = w_cross + 2 * kInDim;
  u16* xrow = x0 + (size_t)b * kInPad;
  float u = 0.f, v = 0.f, w = 0.f;
  for (int q = tid; q < 416; q += 256) {  // 416 = 1664/4
    int p = q * 4;
    const float* src = emb + ((size_t)(p >> 6) * kVocab + idx) * kEmb + (p & 63);
    float4 val = *(const float4*)src;
    float4 wp  = *(const float4*)(Wp + p);
    u += val.x * wc2[p] + val.y * wc2[p + 1] + val.z * wc2[p + 2] + val.w * wc2[p + 3];
    v += val.x * wp.x + val.y * wp.y + val.z * wp.z + val.w * wp.w;
    w += wp.x + wp.y + wp.z + wp.w;
    ushort4 o;
    o.x = f2b(val.x); o.y = f2b(val.y); o.z = f2b(val.z); o.w = f2b(val.w);
    *(ushort4*)(xrow + p) = o;
  }
  int p = 1664 + tid;
  if (p < kInPad) {
    float val = 0.f;
    if (p < kInDim) {
      val = dense[b * kDense + (p - 1664)];
      float wp = Wp[p];
      u += val * wc2[p];
      v += val * wp;
      w += wp;
    }
    xrow[p] = f2b(val);
  }
  #pragma unroll
  for (int off = 32; off; off >>= 1) {
    u += __shfl_down(u, off, 64);
    v += __shfl_down(v, off, 64);
    w += __shfl_down(w, off, 64);
  }
  __shared__ float su[4], sv[4], sw[4];
  int lane = tid & 63, wv = tid >> 6;
  if (lane == 0) { su[wv] = u; sv[wv] = v; sw[wv] = w; }
  __syncthreads();
  if (tid == 0) {
    float uu = su[0] + su[1] + su[2] + su[3];
    float vv = sv[0] + sv[1] + sv[2] + sv[3];
    float ww = sw[0] + sw[1] + sw[2] + sw[3];
    crossc[b] = (1.f + uu) * vv + b_cross[2] * ww;
  }
}

// ---------- per-column sums / sumsq over batch (x0 only), short8 vectorized ----------
// Block covers 64 cols x 512 rows. Thread: cg=tid&7 (8-col group), rg=tid>>3
// (row subgroup, 32 of them); 16 rows/thread, 16B/load (G13: no scalar bf16).
__global__ __launch_bounds__(256) void colstats_kernel(
    const u16* __restrict__ X, int ld, float* __restrict__ sum, float* __restrict__ sq) {
  const int tid = threadIdx.x;
  const int cg = tid & 7;
  const int rg = tid >> 3;            // 0..31
  const int col0 = blockIdx.x * 64 + cg * 8;
  const int r0 = blockIdx.y * 512 + rg;
  float s[8] = {0,0,0,0,0,0,0,0}, s2[8] = {0,0,0,0,0,0,0,0};
  for (int i = 0; i < 16; ++i) {
    int r = r0 + i * 32;
    short8v v = *(const short8v*)(X + (size_t)r * ld + col0);
    #pragma unroll
    for (int e = 0; e < 8; ++e) {
      float f = b2f((u16)v[e]);
      s[e] += f; s2[e] += f * f;
    }
  }
  __shared__ float sh[256][17];       // 17: pad to break 8-way bank alias
  #pragma unroll
  for (int e = 0; e < 8; ++e) { sh[tid][e] = s[e]; sh[tid][e + 8] = s2[e]; }
  __syncthreads();
  if (tid < 64) {
    int cgr = tid >> 3, e = tid & 7;
    float ts = 0.f, tq = 0.f;
    #pragma unroll
    for (int g = 0; g < 32; ++g) {
      ts += sh[g * 8 + cgr][e];
      tq += sh[g * 8 + cgr][e + 8];
    }
    int col = blockIdx.x * 64 + cgr * 8 + e;
    atomicAdd(&sum[col], ts);
    atomicAdd(&sq[col],  tq);
  }
}

// ---------- fused layer-boundary: BN-affine from stats + transpose + scale-fold
//            + wave-reduced bias-fold. ----------
__global__ void fold_kernel(const float* __restrict__ W, const float* __restrict__ sum,
                            const float* __restrict__ sq, const float* __restrict__ g,
                            const float* __restrict__ bb, float invM,
                            u16* __restrict__ Wt, float* __restrict__ bfold,
                            int K, int N, int Kp) {
  __shared__ float t[64][65];
  int kb = blockIdx.x * 64;
  int nb = blockIdx.y * 64;
  int c  = threadIdx.x & 63;
  int r0 = threadIdx.x >> 6;   // 0..3
  #pragma unroll
  for (int rr = 0; rr < 64; rr += 4) {
    int k = kb + rr + r0;
    t[rr + r0][c] = (k < K) ? W[(size_t)k * N + nb + c] : 0.f;
  }
  __syncthreads();
  int k = kb + c;
  float a = 0.f, cc = 0.f;
  if (k < K) {
    float mu  = sum[k] * invM;
    float var = sq[k] * invM - mu * mu;
    a  = g[k] * rsqrtf(var + kEps);
    cc = bb[k] - a * mu;
  }
  #pragma unroll
  for (int rr = 0; rr < 64; rr += 4) {
    int n = nb + rr + r0;
    float w = t[c][rr + r0];
    Wt[(size_t)n * Kp + k] = f2b(w * a);
    float part = cc * w;
    #pragma unroll
    for (int off = 32; off; off >>= 1) part += __shfl_xor(part, off, 64);
    if (c == 0) atomicAdd(&bfold[n], part);
  }
}

// ---------- 128x128 MFMA GEMM (verified m97-structure) for layer 3 ----------
__global__ __launch_bounds__(256) void gemm_kernel(
    const u16* __restrict__ A, const u16* __restrict__ Bt,
    const float* __restrict__ bias, const float* __restrict__ bfold,
    u16* __restrict__ Z, float* __restrict__ sum, float* __restrict__ sq,
    int M, int N, int Kp) {
  __shared__ char lds[32768];
  char* ldsA = lds;
  char* ldsB = lds + 16384;
  const int tid  = threadIdx.x;
  const int lane = tid & 63;
  const int wv   = tid >> 6;
  const int wr = wv >> 1, wc = wv & 1;
  const int r16 = lane & 15, kg = lane >> 4;

  const int L   = blockIdx.y * gridDim.x + blockIdx.x;
  const int xcd = L & 7;
  const int j   = L >> 3;
  const int mb  = xcd * 16 + (j & 15);
  const int nb  = j >> 4;
  const int m0 = mb * 128;
  const int n0 = nb * 128;
  const int ldb = Kp * 2;

  const char* gA = (const char*)A + (size_t)m0 * ldb;
  const char* gB = (const char*)Bt + (size_t)n0 * ldb;

  const char* srcA[4]; const char* srcB[4]; int dst[4];
  #pragma unroll
  for (int rr = 0; rr < 4; ++rr) {
    int lb  = (rr * 256 + tid) * 16;
    int row = lb >> 7;
    int kb  = lb & 127;
    int kbs = kb ^ ((row & 7) << 4);
    dst[rr]  = lb;
    srcA[rr] = gA + (size_t)row * ldb + kbs;
    srcB[rr] = gB + (size_t)row * ldb + kbs;
  }

  f32x4 acc[4][4];
  #pragma unroll
  for (int m = 0; m < 4; ++m)
    #pragma unroll
    for (int n = 0; n < 4; ++n) acc[m][n] = (f32x4){0.f, 0.f, 0.f, 0.f};

  for (int k0 = 0; k0 < Kp; k0 += 64) {
    __syncthreads();
    #pragma unroll
    for (int rr = 0; rr < 4; ++rr)
      __builtin_amdgcn_global_load_lds((const AS1 unsigned*)(srcA[rr] + k0 * 2),
                                       (AS3 unsigned*)(ldsA + dst[rr]), 16, 0, 0);
    #pragma unroll
    for (int rr = 0; rr < 4; ++rr)
      __builtin_amdgcn_global_load_lds((const AS1 unsigned*)(srcB[rr] + k0 * 2),
                                       (AS3 unsigned*)(ldsB + dst[rr]), 16, 0, 0);
    asm volatile("s_waitcnt vmcnt(0)" ::: "memory");
    __syncthreads();
    #pragma unroll
    for (int kk = 0; kk < 2; ++kk) {
      short8v av[4], bv[4];
      #pragma unroll
      for (int m = 0; m < 4; ++m) {
        int row = wr * 64 + m * 16 + r16;
        int kb  = (kk * 64 + kg * 16) ^ ((row & 7) << 4);
        av[m] = *(const short8v*)(ldsA + row * 128 + kb);
      }
      #pragma unroll
      for (int n = 0; n < 4; ++n) {
        int row = wc * 64 + n * 16 + r16;
        int kb  = (kk * 64 + kg * 16) ^ ((row & 7) << 4);
        bv[n] = *(const short8v*)(ldsB + row * 128 + kb);
      }
      #pragma unroll
      for (int m = 0; m < 4; ++m)
        #pragma unroll
        for (int n = 0; n < 4; ++n)
          acc[m][n] = __builtin_amdgcn_mfma_f32_16x16x32_bf16(av[m], bv[n], acc[m][n], 0, 0, 0);
    }
  }
  #pragma unroll
  for (int n = 0; n < 4; ++n) {
    int col = n0 + wc * 64 + n * 16 + r16;
    float bs = bias[col] + bfold[col];
    float ps = 0.f, pq = 0.f;
    #pragma unroll
    for (int m = 0; m < 4; ++m) {
      int rbase = m0 + wr * 64 + m * 16 + kg * 4;
      #pragma unroll
      for (int j2 = 0; j2 < 4; ++j2) {
        float val = acc[m][n][j2] + bs;
        Z[(size_t)(rbase + j2) * N + col] = f2b(val);
        ps += val; pq += val * val;
      }
    }
    ps += __shfl_xor(ps, 16, 64); ps += __shfl_xor(ps, 32, 64);
    pq += __shfl_xor(pq, 16, 64); pq += __shfl_xor(pq, 32, 64);
    if (lane < 16) {
      atomicAdd(&sum[col], ps);
      atomicAdd(&sq[col],  pq);
    }
  }
}

// ===== shared barrier macros for pipelined kernels =====
#define BAR_VMN(N)                                                              \
  {                                                                             \
    asm volatile("s_waitcnt vmcnt(" #N ")" ::: "memory");                       \
    __builtin_amdgcn_sched_barrier(0);                                          \
    __builtin_amdgcn_s_barrier();                                               \
    __builtin_amdgcn_sched_barrier(0);                                          \
  }
#define BAR_NOVM()                                                              \
  {                                                                             \
    __builtin_amdgcn_sched_barrier(0);                                          \
    __builtin_amdgcn_s_barrier();                                               \
    __builtin_amdgcn_sched_barrier(0);                                          \
  }

// ---------- 256x256 8-wave 4-phase/K-tile pipelined GEMM (layer 1) ----------
#define STAGE(OP, H, TILE)                                                      \
  {                                                                             \
    const char* sb = ((OP) ? gB : gA) + (size_t)((H) * 128) * ldb               \
                     + (size_t)(TILE) * 128 + srcoff;                           \
    char* db = lds + (((TILE) & 1) << 16) + ((OP) << 15) + ((H) << 14) + tid * 16; \
    __builtin_amdgcn_global_load_lds((const AS1 unsigned*)sb,                   \
                                     (AS3 unsigned*)db, 16, 0, 0);              \
    __builtin_amdgcn_global_load_lds((const AS1 unsigned*)(sb + 64 * (size_t)ldb), \
                                     (AS3 unsigned*)(db + 8192), 16, 0, 0);     \
  }

#define PHASE(T, MH, NH)                                                        \
  {                                                                             \
    char* la  = lds + (((T) & 1) << 16);                                        \
    char* lbp = la + 32768;                                                     \
    short8v av[4][2], bv[2][2];                                                 \
    _Pragma("unroll")                                                           \
    for (int fm = 0; fm < 4; ++fm) {                                            \
      int row = (MH) * 128 + wr * 64 + fm * 16 + r16;                           \
      _Pragma("unroll")                                                         \
      for (int kk = 0; kk < 2; ++kk) {                                          \
        int kb = (kk * 64 + kg * 16) ^ ((row & 7) << 4);                        \
        av[fm][kk] = *(const short8v*)(la + row * 128 + kb);                    \
      }                                                                         \
    }                                                                           \
    _Pragma("unroll")                                                           \
    for (int fn = 0; fn < 2; ++fn) {                                            \
      int row = (NH) * 128 + wc * 32 + fn * 16 + r16;                           \
      _Pragma("unroll")                                                         \
      for (int kk = 0; kk < 2; ++kk) {                                          \
        int kb = (kk * 64 + kg * 16) ^ ((row & 7) << 4);                        \
        bv[fn][kk] = *(const short8v*)(lbp + row * 128 + kb);                   \
      }                                                                         \
    }                                                                           \
    __builtin_amdgcn_s_setprio(1);                                              \
    _Pragma("unroll")                                                           \
    for (int fm = 0; fm < 4; ++fm)                                              \
      _Pragma("unroll")                                                         \
      for (int fn = 0; fn < 2; ++fn)                                            \
        _Pragma("unroll")                                                       \
        for (int kk = 0; kk < 2; ++kk)                                          \
          acc[(MH) * 4 + fm][(NH) * 2 + fn] =                                   \
              __builtin_amdgcn_mfma_f32_16x16x32_bf16(                          \
                  av[fm][kk], bv[fn][kk],                                       \
                  acc[(MH) * 4 + fm][(NH) * 2 + fn], 0, 0, 0);                  \
    __builtin_amdgcn_s_setprio(0);                                              \
  }

__global__ __launch_bounds__(512, 2) void gemm256_kernel(
    const u16* __restrict__ A, const u16* __restrict__ Bt,
    const float* __restrict__ bias, const float* __restrict__ bfold,
    u16* __restrict__ Z, float* __restrict__ sum, float* __restrict__ sq,
    int M, int N, int Kp) {
  __shared__ char lds[131072];
  const int tid  = threadIdx.x;
  const int lane = tid & 63;
  const int wid  = tid >> 6;           // 0..7
  const int wr = wid >> 2, wc = wid & 3;  // 2M x 4N waves
  const int r16 = lane & 15, kg = lane >> 4;

  const int nmb = M >> 8;
  const int cpx = nmb >> 3;
  const int L   = blockIdx.x;
  const int xcd = L & 7;
  const int jj  = L >> 3;
  const int mb  = xcd * cpx + (jj % cpx);
  const int nb  = jj / cpx;
  const int m0  = mb * 256;
  const int n0  = nb * 256;
  const int ldb = Kp * 2;
  const int nt  = Kp >> 6;

  const char* gA = (const char*)A + (size_t)m0 * ldb;
  const char* gB = (const char*)Bt + (size_t)n0 * ldb;
  const int row0 = tid >> 3;
  const int kbs  = ((tid & 7) * 16) ^ ((row0 & 7) << 4);
  const size_t srcoff = (size_t)row0 * ldb + kbs;

  f32x4 acc[8][4];
  #pragma unroll
  for (int m = 0; m < 8; ++m)
    #pragma unroll
    for (int n = 0; n < 4; ++n) acc[m][n] = (f32x4){0.f, 0.f, 0.f, 0.f};

  STAGE(0, 0, 0); STAGE(1, 0, 0); STAGE(1, 1, 0); STAGE(0, 1, 0);
  STAGE(0, 0, 1); STAGE(1, 0, 1);
  BAR_VMN(8);

  const int Tmain = nt - 2;
  for (int T = 0; T < Tmain; ++T) {
    STAGE(1, 1, T + 1);
    PHASE(T, 0, 0);
    BAR_VMN(8);
    STAGE(0, 1, T + 1);
    PHASE(T, 0, 1);
    BAR_VMN(8);
    if (T + 2 < nt) STAGE(0, 0, T + 2);
    PHASE(T, 1, 0);
    BAR_NOVM();
    if (T + 2 < nt) STAGE(1, 0, T + 2);
    PHASE(T, 1, 1);
    BAR_VMN(8);
  }
  for (int T = Tmain; T < nt; ++T) {
    if (T + 1 < nt) STAGE(1, 1, T + 1);
    PHASE(T, 0, 0);
    BAR_VMN(0);
    if (T + 1 < nt) STAGE(0, 1, T + 1);
    PHASE(T, 0, 1);
    BAR_VMN(0);
    PHASE(T, 1, 0);
    BAR_NOVM();
    PHASE(T, 1, 1);
    BAR_VMN(0);
  }

  #pragma unroll
  for (int nh = 0; nh < 2; ++nh)
    #pragma unroll
    for (int fn = 0; fn < 2; ++fn) {
      int col = n0 + nh * 128 + wc * 32 + fn * 16 + r16;
      float bs = bias[col] + bfold[col];
      float ps = 0.f, pq = 0.f;
      #pragma unroll
      for (int mh = 0; mh < 2; ++mh)
        #pragma unroll
        for (int fm = 0; fm < 4; ++fm) {
          int rbase = m0 + mh * 128 + wr * 64 + fm * 16 + kg * 4;
          #pragma unroll
          for (int j2 = 0; j2 < 4; ++j2) {
            float val = acc[mh * 4 + fm][nh * 2 + fn][j2] + bs;
            Z[(size_t)(rbase + j2) * N + col] = f2b(val);
            ps += val; pq += val * val;
          }
        }
      ps += __shfl_xor(ps, 16, 64); ps += __shfl_xor(ps, 32, 64);
      pq += __shfl_xor(pq, 16, 64); pq += __shfl_xor(pq, 32, 64);
      if (lane < 16) {
        atomicAdd(&sum[col], ps);
        atomicAdd(&sq[col],  pq);
      }
    }
}

// ---------- 256x128-tile 8-wave 2-phase/K-tile pipelined GEMM (layer 2) ----------
#define STAGE2A(H, TILE)                                                        \
  {                                                                             \
    const char* sb = gA + (size_t)((H) * 128) * ldb + (size_t)(TILE) * 128 + srcoff; \
    char* db = lds + (((TILE) & 1) << 15) + ((H) << 14) + tid * 16;             \
    __builtin_amdgcn_global_load_lds((const AS1 unsigned*)sb,                   \
                                     (AS3 unsigned*)db, 16, 0, 0);              \
    __builtin_amdgcn_global_load_lds((const AS1 unsigned*)(sb + 64 * (size_t)ldb), \
                                     (AS3 unsigned*)(db + 8192), 16, 0, 0);     \
  }
#define STAGE2B(TILE)                                                           \
  {                                                                             \
    const char* sb = gB + (size_t)(TILE) * 128 + srcoff;                        \
    char* db = lds + 65536 + (((TILE) & 1) << 14) + tid * 16;                   \
    __builtin_amdgcn_global_load_lds((const AS1 unsigned*)sb,                   \
                                     (AS3 unsigned*)db, 16, 0, 0);              \
    __builtin_amdgcn_global_load_lds((const AS1 unsigned*)(sb + 64 * (size_t)ldb), \
                                     (AS3 unsigned*)(db + 8192), 16, 0, 0);     \
  }

#define PHASE2(T, MH)                                                           \
  {                                                                             \
    char* la  = lds + (((T) & 1) << 15) + ((MH) << 14);                         \
    char* lbp = lds + 65536 + (((T) & 1) << 14);                                \
    short8v av[4][2], bv[2][2];                                                 \
    _Pragma("unroll")                                                           \
    for (int fm = 0; fm < 4; ++fm) {                                            \
      int row = wr * 64 + fm * 16 + r16;                                        \
      _Pragma("unroll")                                                         \
      for (int kk = 0; kk < 2; ++kk) {                                          \
        int kb = (kk * 64 + kg * 16) ^ ((row & 7) << 4);                        \
        av[fm][kk] = *(const short8v*)(la + row * 128 + kb);                    \
      }                                                                         \
    }                                                                           \
    _Pragma("unroll")                                                           \
    for (int fn = 0; fn < 2; ++fn) {                                            \
      int row = wc * 32 + fn * 16 + r16;                                        \
      _Pragma("unroll")                                                         \
      for (int kk = 0; kk < 2; ++kk) {                                          \
        int kb = (kk * 64 + kg * 16) ^ ((row & 7) << 4);                        \
        bv[fn][kk] = *(const short8v*)(lbp + row * 128 + kb);                   \
      }                                                                         \
    }                                                                           \
    __builtin_amdgcn_s_setprio(1);                                              \
    _Pragma("unroll")                                                           \
    for (int fm = 0; fm < 4; ++fm)                                              \
      _Pragma("unroll")                                                         \
      for (int fn = 0; fn < 2; ++fn)                                            \
        _Pragma("unroll")                                                       \
        for (int kk = 0; kk < 2; ++kk)                                          \
          acc[(MH) * 4 + fm][fn] =                                              \
              __builtin_amdgcn_mfma_f32_16x16x32_bf16(                          \
                  av[fm][kk], bv[fn][kk], acc[(MH) * 4 + fm][fn], 0, 0, 0);     \
    __builtin_amdgcn_s_setprio(0);                                              \
  }

__global__ __launch_bounds__(512, 2) void gemm256x128_kernel(
    const u16* __restrict__ A, const u16* __restrict__ Bt,
    const float* __restrict__ bias, const float* __restrict__ bfold,
    u16* __restrict__ Z, float* __restrict__ sum, float* __restrict__ sq,
    int M, int N, int Kp) {
  __shared__ char lds[98304];
  const int tid  = threadIdx.x;
  const int lane = tid & 63;
  const int wid  = tid >> 6;              // 0..7
  const int wr = wid >> 2, wc = wid & 3;  // 2M x 4N
  const int r16 = lane & 15, kg = lane >> 4;

  const int nmb = M >> 8;                 // 64
  const int cpx = nmb >> 3;               // 8
  const int L   = blockIdx.x;
  const int xcd = L & 7;
  const int jj  = L >> 3;
  const int mb  = xcd * cpx + (jj % cpx);
  const int nb  = jj / cpx;
  const int m0  = mb * 256;
  const int n0  = nb * 128;
  const int ldb = Kp * 2;
  const int nt  = Kp >> 6;

  const char* gA = (const char*)A + (size_t)m0 * ldb;
  const char* gB = (const char*)Bt + (size_t)n0 * ldb;
  const int row0 = tid >> 3;
  const int kbs  = ((tid & 7) * 16) ^ ((row0 & 7) << 4);
  const size_t srcoff = (size_t)row0 * ldb + kbs;

  f32x4 acc[8][2];
  #pragma unroll
  for (int m = 0; m < 8; ++m)
    #pragma unroll
    for (int n = 0; n < 2; ++n) acc[m][n] = (f32x4){0.f, 0.f, 0.f, 0.f};

  STAGE2A(0, 0); STAGE2B(0); STAGE2A(1, 0);

  const int Tmain = nt - 1;
  for (int T = 0; T < Tmain; ++T) {
    STAGE2A(0, T + 1); STAGE2B(T + 1);   // 4 inst
    BAR_VMN(6);                          // proves A0,B(T)
    PHASE2(T, 0);
    STAGE2A(1, T + 1);                   // 2 inst
    BAR_VMN(6);                          // proves A1(T)
    PHASE2(T, 1);
    BAR_NOVM();
  }
  BAR_VMN(2);
  PHASE2(nt - 1, 0);
  BAR_VMN(0);
  PHASE2(nt - 1, 1);

  #pragma unroll
  for (int fn = 0; fn < 2; ++fn) {
    int col = n0 + wc * 32 + fn * 16 + r16;
    float bs = bias[col] + bfold[col];
    float ps = 0.f, pq = 0.f;
    #pragma unroll
    for (int mh = 0; mh < 2; ++mh)
      #pragma unroll
      for (int fm = 0; fm < 4; ++fm) {
        int rbase = m0 + mh * 128 + wr * 64 + fm * 16 + kg * 4;
        #pragma unroll
        for (int j2 = 0; j2 < 4; ++j2) {
          float val = acc[mh * 4 + fm][fn][j2] + bs;
          Z[(size_t)(rbase + j2) * N + col] = f2b(val);
          ps += val; pq += val * val;
        }
      }
    ps += __shfl_xor(ps, 16, 64); ps += __shfl_xor(ps, 32, 64);
    pq += __shfl_xor(pq, 16, 64); pq += __shfl_xor(pq, 32, 64);
    if (lane < 16) {
      atomicAdd(&sum[col], ps);
      atomicAdd(&sq[col],  pq);
    }
  }
}

// ---------- final: BN3 inline from stats + concat-dot + sigmoid (float32 out) ----------
__global__ void final_kernel(const u16* __restrict__ z3, const float* __restrict__ sum3,
                             const float* __restrict__ sq3, const float* __restrict__ g3,
                             const float* __restrict__ b3, float invM,
                             const float* __restrict__ Wp, const float* __restrict__ bp,
                             const float* __restrict__ crossc, float* __restrict__ out) {
  int wv = threadIdx.x >> 6, lane = threadIdx.x & 63;
  int b = blockIdx.x * 4 + wv;
  const float* wph = Wp + kInDim;
  float s = 0.f;
  #pragma unroll
  for (int k = lane; k < kH3; k += 64) {
    float mu  = sum3[k] * invM;
    float var = sq3[k] * invM - mu * mu;
    float a   = g3[k] * rsqrtf(var + kEps);
    float cc  = b3[k] - a * mu;
    float h = a * b2f(z3[(size_t)b * kH3 + k]) + cc;
    s += h * wph[k];
  }
  #pragma unroll
  for (int off = 32; off; off >>= 1) s += __shfl_down(s, off, 64);
  if (lane == 0) {
    float logit = s + crossc[b] + bp[0];
    out[b] = 1.f / (1.f + expf(-logit));
  }
}

// ---------- workspace layout ----------
constexpr size_t OFF_X0    = 0;                                   // 16384*1728*2
constexpr size_t OFF_Z1    = OFF_X0 + (size_t)kBatch * kInPad * 2;
constexpr size_t OFF_Z2    = OFF_Z1 + (size_t)kBatch * kH1 * 2;
constexpr size_t OFF_Z3    = OFF_Z2 + (size_t)kBatch * kH2 * 2;
constexpr size_t OFF_W1T   = OFF_Z3 + (size_t)kBatch * kH3 * 2;
constexpr size_t OFF_W2T   = OFF_W1T + (size_t)kH1 * kInPad * 2;
constexpr size_t OFF_W3T   = OFF_W2T + (size_t)kH2 * kH1 * 2;
constexpr size_t OFF_CROSS = OFF_W3T + (size_t)kH3 * kH2 * 2;
constexpr size_t OFF_STATS = OFF_CROSS + (size_t)kBatch * 4;
constexpr size_t OFF_BF    = OFF_STATS + (size_t)kStatsFloats * 4;
// total ~115 MB

extern "C" void kernel_launch(void* const* d_in, const int* in_sizes, int n_in,
                              void* d_out, int out_size, void* d_ws, size_t ws_size,
                              hipStream_t stream) {
  const int*   sparse  = (const int*)d_in[0];
  const float* dense   = (const float*)d_in[1];
  const float* emb     = (const float*)d_in[2];
  const float* w_cross = (const float*)d_in[3];
  const float* b_cross = (const float*)d_in[4];
  const float* bn0_g = (const float*)d_in[5],  *bn0_b = (const float*)d_in[6];
  const float* W1    = (const float*)d_in[7],  *bias1 = (const float*)d_in[8];
  const float* bn1_g = (const float*)d_in[9],  *bn1_b = (const float*)d_in[10];
  const float* W2    = (const float*)d_in[11], *bias2 = (const float*)d_in[12];
  const float* bn2_g = (const float*)d_in[13], *bn2_b = (const float*)d_in[14];
  const float* W3    = (const float*)d_in[15], *bias3 = (const float*)d_in[16];
  const float* bn3_g = (const float*)d_in[17], *bn3_b = (const float*)d_in[18];
  const float* Wp    = (const float*)d_in[19], *bp    = (const float*)d_in[20];

  char* ws = (char*)d_ws;
  u16* x0  = (u16*)(ws + OFF_X0);
  u16* z1  = (u16*)(ws + OFF_Z1);
  u16* z2  = (u16*)(ws + OFF_Z2);
  u16* z3  = (u16*)(ws + OFF_Z3);
  u16* W1t = (u16*)(ws + OFF_W1T);
  u16* W2t = (u16*)(ws + OFF_W2T);
  u16* W3t = (u16*)(ws + OFF_W3T);
  float* crossc = (float*)(ws + OFF_CROSS);
  float* stats  = (float*)(ws + OFF_STATS);
  float* sum0 = stats,            *sq0 = stats + kInPad;
  float* sum1 = sq0 + kInPad,     *sq1 = sum1 + kH1;
  float* sum2 = sq1 + kH1,        *sq2 = sum2 + kH2;
  float* sum3 = sq2 + kH2,        *sq3 = sum3 + kH3;
  float* bfold = (float*)(ws + OFF_BF);
  float* b1f = bfold, *b2f = b1f + kH1, *b3f = b2f + kH2;
  float* out = (float*)d_out;

  const float invM = 1.f / (float)kBatch;

  // gather also zeroes stats (block 0) and computes per-block sum(Wp) locally
  gather_kernel<<<kBatch, 256, 0, stream>>>(sparse, dense, emb, w_cross, b_cross, Wp,
                                            x0, crossc, stats);

  // BN0 stats -> fold into W1/bias1
  colstats_kernel<<<dim3(kInPad / 64, kBatch / 512), 256, 0, stream>>>(x0, kInPad, sum0, sq0);
  fold_kernel<<<dim3(kInPad / 64, kH1 / 64), 256, 0, stream>>>(
      W1, sum0, sq0, bn0_g, bn0_b, invM, W1t, b1f, kInDim, kH1, kInPad);

  // layer 1: 256x256 pipelined GEMM (stats fused)
  gemm256_kernel<<<(kBatch / 256) * (kH1 / 256), 512, 0, stream>>>(
      x0, W1t, bias1, b1f, z1, sum1, sq1, kBatch, kH1, kInPad);
  fold_kernel<<<dim3(kH1 / 64, kH2 / 64), 256, 0, stream>>>(
      W2, sum1, sq1, bn1_g, bn1_b, invM, W2t, b2f, kH1, kH2, kH1);

  // layer 2: 256x128 pipelined GEMM (stats fused)
  gemm256x128_kernel<<<(kBatch / 256) * (kH2 / 128), 512, 0, stream>>>(
      z1, W2t, bias2, b2f, z2, sum2, sq2, kBatch, kH2, kH1);
  fold_kernel<<<dim3(kH2 / 64, kH3 / 64), 256, 0, stream>>>(
      W3, sum2, sq2, bn2_g, bn2_b, invM, W3t, b3f, kH2, kH3, kH2);

  // layer 3 (BN3 inline in final)
  gemm_kernel<<<dim3(kH3 / 128, kBatch / 128), 256, 0, stream>>>(
      z2, W3t, bias3, b3f, z3, sum3, sq3, kBatch, kH3, kH2);

  final_kernel<<<kBatch / 4, 256, 0, stream>>>(z3, sum3, sq3, bn3_g, bn3_b, invM,
                                               Wp, bp, crossc, out);
}

// Round 14
// 192.675 us; speedup vs baseline: 1.3824x; 1.0268x over previous
//
#include <hip/hip_runtime.h>
#include <hip/hip_bf16.h>
#include <cstdint>
#include <cstddef>

#define AS1 __attribute__((address_space(1)))
#define AS3 __attribute__((address_space(3)))

typedef __attribute__((ext_vector_type(8))) short short8v;
typedef __attribute__((ext_vector_type(4))) float f32x4;
typedef unsigned short u16;

constexpr int kBatch = 16384;
constexpr int kNSp   = 26;
constexpr int kVocab = 50000;
constexpr int kEmb   = 64;
constexpr int kInDim = 1677;   // 26*64 + 13
constexpr int kInPad = 1728;   // padded to x64 (nt=27 odd-safe in gemm256)
constexpr int kDense = 13;
constexpr int kH1 = 1024, kH2 = 512, kH3 = 256;
constexpr float kEps = 1e-5f;

constexpr int kStatsFloats = 2 * (kInPad + kH1 + kH2 + kH3);   // 7040
constexpr int kBfFloats    = kH1 + kH2 + kH3;                  // 1792

// ---------- bf16 helpers (bits held in u16) ----------
__device__ __forceinline__ float b2f(u16 s) {
  unsigned u = ((unsigned)s) << 16;
  union { unsigned u; float f; } c; c.u = u; return c.f;
}
__device__ __forceinline__ u16 f2b(float f) {
  __hip_bfloat16 h = __float2bfloat16(f);   // RNE
  return __builtin_bit_cast(u16, h);
}

// ---------- gather: build raw x0 (bf16, padded) + per-row cross contribution ----------
__global__ void gather_kernel(const int* __restrict__ sparse, const float* __restrict__ dense,
                              const float* __restrict__ emb, const float* __restrict__ w_cross,
                              const float* __restrict__ b_cross, const float* __restrict__ Wp,
                              u16* __restrict__ x0, float* __restrict__ crossc,
                              float* __restrict__ stats) {
  const int b = blockIdx.x;
  const int tid = threadIdx.x;
  if (b == 0) {   // zero stats + bfold accumulators
    for (int i = tid; i < kStatsFloats + kBfFloats; i += 256) stats[i] = 0.f;
  }
  const int idx = sparse[b * kNSp];       // only column 0 is used by the reference
  const float* wc2 = w_cross + 2 * kInDim;
  u16* xrow = x0 + (size_t)b * kInPad;
  float u = 0.f, v = 0.f, w = 0.f;
  for (int q = tid; q < 416; q += 256) {  // 416 = 1664/4
    int p = q * 4;
    const float* src = emb + ((size_t)(p >> 6) * kVocab + idx) * kEmb + (p & 63);
    float4 val = *(const float4*)src;
    float4 wp  = *(const float4*)(Wp + p);
    u += val.x * wc2[p] + val.y * wc2[p + 1] + val.z * wc2[p + 2] + val.w * wc2[p + 3];
    v += val.x * wp.x + val.y * wp.y + val.z * wp.z + val.w * wp.w;
    w += wp.x + wp.y + wp.z + wp.w;
    ushort4 o;
    o.x = f2b(val.x); o.y = f2b(val.y); o.z = f2b(val.z); o.w = f2b(val.w);
    *(ushort4*)(xrow + p) = o;
  }
  int p = 1664 + tid;
  if (p < kInPad) {
    float val = 0.f;
    if (p < kInDim) {
      val = dense[b * kDense + (p - 1664)];
      float wp = Wp[p];
      u += val * wc2[p];
      v += val * wp;
      w += wp;
    }
    xrow[p] = f2b(val);
  }
  #pragma unroll
  for (int off = 32; off; off >>= 1) {
    u += __shfl_down(u, off, 64);
    v += __shfl_down(v, off, 64);
    w += __shfl_down(w, off, 64);
  }
  __shared__ float su[4], sv[4], sw[4];
  int lane = tid & 63, wv = tid >> 6;
  if (lane == 0) { su[wv] = u; sv[wv] = v; sw[wv] = w; }
  __syncthreads();
  if (tid == 0) {
    float uu = su[0] + su[1] + su[2] + su[3];
    float vv = sv[0] + sv[1] + sv[2] + sv[3];
    float ww = sw[0] + sw[1] + sw[2] + sw[3];
    crossc[b] = (1.f + uu) * vv + b_cross[2] * ww;
  }
}

// ---------- per-column sums / sumsq over batch (x0 only), short8 vectorized ----------
__global__ __launch_bounds__(256) void colstats_kernel(
    const u16* __restrict__ X, int ld, float* __restrict__ sum, float* __restrict__ sq) {
  const int tid = threadIdx.x;
  const int cg = tid & 7;
  const int rg = tid >> 3;            // 0..31
  const int col0 = blockIdx.x * 64 + cg * 8;
  const int r0 = blockIdx.y * 512 + rg;
  float s[8] = {0,0,0,0,0,0,0,0}, s2[8] = {0,0,0,0,0,0,0,0};
  for (int i = 0; i < 16; ++i) {
    int r = r0 + i * 32;
    short8v v = *(const short8v*)(X + (size_t)r * ld + col0);
    #pragma unroll
    for (int e = 0; e < 8; ++e) {
      float f = b2f((u16)v[e]);
      s[e] += f; s2[e] += f * f;
    }
  }
  __shared__ float sh[256][17];       // 17: pad to break 8-way bank alias
  #pragma unroll
  for (int e = 0; e < 8; ++e) { sh[tid][e] = s[e]; sh[tid][e + 8] = s2[e]; }
  __syncthreads();
  if (tid < 64) {
    int cgr = tid >> 3, e = tid & 7;
    float ts = 0.f, tq = 0.f;
    #pragma unroll
    for (int g = 0; g < 32; ++g) {
      ts += sh[g * 8 + cgr][e];
      tq += sh[g * 8 + cgr][e + 8];
    }
    int col = blockIdx.x * 64 + cgr * 8 + e;
    atomicAdd(&sum[col], ts);
    atomicAdd(&sq[col],  tq);
  }
}

// ---------- fused layer-boundary: BN-affine from stats + transpose + scale-fold
//            + wave-reduced bias-fold. ----------
__global__ void fold_kernel(const float* __restrict__ W, const float* __restrict__ sum,
                            const float* __restrict__ sq, const float* __restrict__ g,
                            const float* __restrict__ bb, float invM,
                            u16* __restrict__ Wt, float* __restrict__ bfold,
                            int K, int N, int Kp) {
  __shared__ float t[64][65];
  int kb = blockIdx.x * 64;
  int nb = blockIdx.y * 64;
  int c  = threadIdx.x & 63;
  int r0 = threadIdx.x >> 6;   // 0..3
  #pragma unroll
  for (int rr = 0; rr < 64; rr += 4) {
    int k = kb + rr + r0;
    t[rr + r0][c] = (k < K) ? W[(size_t)k * N + nb + c] : 0.f;
  }
  __syncthreads();
  int k = kb + c;
  float a = 0.f, cc = 0.f;
  if (k < K) {
    float mu  = sum[k] * invM;
    float var = sq[k] * invM - mu * mu;
    a  = g[k] * rsqrtf(var + kEps);
    cc = bb[k] - a * mu;
  }
  #pragma unroll
  for (int rr = 0; rr < 64; rr += 4) {
    int n = nb + rr + r0;
    float w = t[c][rr + r0];
    Wt[(size_t)n * Kp + k] = f2b(w * a);
    float part = cc * w;
    #pragma unroll
    for (int off = 32; off; off >>= 1) part += __shfl_xor(part, off, 64);
    if (c == 0) atomicAdd(&bfold[n], part);
  }
}

// ===== shared barrier macros for pipelined kernels =====
#define BAR_VMN(N)                                                              \
  {                                                                             \
    asm volatile("s_waitcnt vmcnt(" #N ")" ::: "memory");                       \
    __builtin_amdgcn_sched_barrier(0);                                          \
    __builtin_amdgcn_s_barrier();                                               \
    __builtin_amdgcn_sched_barrier(0);                                          \
  }
#define BAR_NOVM()                                                              \
  {                                                                             \
    __builtin_amdgcn_sched_barrier(0);                                          \
    __builtin_amdgcn_s_barrier();                                               \
    __builtin_amdgcn_sched_barrier(0);                                          \
  }

// ---------- 128x128 pipelined MFMA GEMM (layer 3): counted-vmcnt single phase ----------
// A dbuf 2x16KB @0, B dbuf 2x16KB @32768. Per K-tile T: STAGE(T+1)[8 insts] ->
// vmcnt(8)+barrier (oldest 8 = tile T's loads done) -> ds_read + 32 MFMA ->
// reads-done barrier (buf[(T+2)&1] == buf[T&1] overwritten only next iter).
// Tail: vmcnt(0). 64KB LDS -> 2 blocks/CU.
__global__ __launch_bounds__(256) void gemm_kernel(
    const u16* __restrict__ A, const u16* __restrict__ Bt,
    const float* __restrict__ bias, const float* __restrict__ bfold,
    u16* __restrict__ Z, float* __restrict__ sum, float* __restrict__ sq,
    int M, int N, int Kp) {
  __shared__ char lds[65536];
  const int tid  = threadIdx.x;
  const int lane = tid & 63;
  const int wv   = tid >> 6;
  const int wr = wv >> 1, wc = wv & 1;
  const int r16 = lane & 15, kg = lane >> 4;

  const int L   = blockIdx.y * gridDim.x + blockIdx.x;
  const int xcd = L & 7;
  const int j   = L >> 3;
  const int mb  = xcd * 16 + (j & 15);
  const int nb  = j >> 4;
  const int m0 = mb * 128;
  const int n0 = nb * 128;
  const int ldb = Kp * 2;
  const int nt  = Kp >> 6;

  const char* gA = (const char*)A + (size_t)m0 * ldb;
  const char* gB = (const char*)Bt + (size_t)n0 * ldb;

  const char* srcA[4]; const char* srcB[4]; int dst[4];
  #pragma unroll
  for (int rr = 0; rr < 4; ++rr) {
    int lb  = (rr * 256 + tid) * 16;
    int row = lb >> 7;
    int kb  = lb & 127;
    int kbs = kb ^ ((row & 7) << 4);
    dst[rr]  = lb;
    srcA[rr] = gA + (size_t)row * ldb + kbs;
    srcB[rr] = gB + (size_t)row * ldb + kbs;
  }

#define STAGE3(TILE)                                                            \
  {                                                                             \
    char* la = lds + (((TILE) & 1) << 14);                                      \
    char* lb = lds + 32768 + (((TILE) & 1) << 14);                              \
    _Pragma("unroll")                                                           \
    for (int rr = 0; rr < 4; ++rr)                                              \
      __builtin_amdgcn_global_load_lds((const AS1 unsigned*)(srcA[rr] + (size_t)(TILE) * 128), \
                                       (AS3 unsigned*)(la + dst[rr]), 16, 0, 0); \
    _Pragma("unroll")                                                           \
    for (int rr = 0; rr < 4; ++rr)                                              \
      __builtin_amdgcn_global_load_lds((const AS1 unsigned*)(srcB[rr] + (size_t)(TILE) * 128), \
                                       (AS3 unsigned*)(lb + dst[rr]), 16, 0, 0); \
  }

  f32x4 acc[4][4];
  #pragma unroll
  for (int m = 0; m < 4; ++m)
    #pragma unroll
    for (int n = 0; n < 4; ++n) acc[m][n] = (f32x4){0.f, 0.f, 0.f, 0.f};

  STAGE3(0);
  for (int T = 0; T < nt; ++T) {
    if (T + 1 < nt) {
      STAGE3(T + 1);
      BAR_VMN(8);          // oldest 8 (tile T) landed; tile T+1's 8 in flight
    } else {
      BAR_VMN(0);          // tail: drain everything
    }
    {
      char* la  = lds + ((T & 1) << 14);
      char* lbp = lds + 32768 + ((T & 1) << 14);
      #pragma unroll
      for (int kk = 0; kk < 2; ++kk) {
        short8v av[4], bv[4];
        #pragma unroll
        for (int m = 0; m < 4; ++m) {
          int row = wr * 64 + m * 16 + r16;
          int kb  = (kk * 64 + kg * 16) ^ ((row & 7) << 4);
          av[m] = *(const short8v*)(la + row * 128 + kb);
        }
        #pragma unroll
        for (int n = 0; n < 4; ++n) {
          int row = wc * 64 + n * 16 + r16;
          int kb  = (kk * 64 + kg * 16) ^ ((row & 7) << 4);
          bv[n] = *(const short8v*)(lbp + row * 128 + kb);
        }
        __builtin_amdgcn_s_setprio(1);
        #pragma unroll
        for (int m = 0; m < 4; ++m)
          #pragma unroll
          for (int n = 0; n < 4; ++n)
            acc[m][n] = __builtin_amdgcn_mfma_f32_16x16x32_bf16(av[m], bv[n], acc[m][n], 0, 0, 0);
        __builtin_amdgcn_s_setprio(0);
      }
    }
    BAR_NOVM();            // all reads of buf[T&1] done before it is re-staged
  }
#undef STAGE3

  #pragma unroll
  for (int n = 0; n < 4; ++n) {
    int col = n0 + wc * 64 + n * 16 + r16;
    float bs = bias[col] + bfold[col];
    float ps = 0.f, pq = 0.f;
    #pragma unroll
    for (int m = 0; m < 4; ++m) {
      int rbase = m0 + wr * 64 + m * 16 + kg * 4;
      #pragma unroll
      for (int j2 = 0; j2 < 4; ++j2) {
        float val = acc[m][n][j2] + bs;
        Z[(size_t)(rbase + j2) * N + col] = f2b(val);
        ps += val; pq += val * val;
      }
    }
    ps += __shfl_xor(ps, 16, 64); ps += __shfl_xor(ps, 32, 64);
    pq += __shfl_xor(pq, 16, 64); pq += __shfl_xor(pq, 32, 64);
    if (lane < 16) {
      atomicAdd(&sum[col], ps);
      atomicAdd(&sq[col],  pq);
    }
  }
}

// ---------- 256x256 8-wave 4-phase/K-tile pipelined GEMM (layer 1) ----------
#define STAGE(OP, H, TILE)                                                      \
  {                                                                             \
    const char* sb = ((OP) ? gB : gA) + (size_t)((H) * 128) * ldb               \
                     + (size_t)(TILE) * 128 + srcoff;                           \
    char* db = lds + (((TILE) & 1) << 16) + ((OP) << 15) + ((H) << 14) + tid * 16; \
    __builtin_amdgcn_global_load_lds((const AS1 unsigned*)sb,                   \
                                     (AS3 unsigned*)db, 16, 0, 0);              \
    __builtin_amdgcn_global_load_lds((const AS1 unsigned*)(sb + 64 * (size_t)ldb), \
                                     (AS3 unsigned*)(db + 8192), 16, 0, 0);     \
  }

#define PHASE(T, MH, NH)                                                        \
  {                                                                             \
    char* la  = lds + (((T) & 1) << 16);                                        \
    char* lbp = la + 32768;                                                     \
    short8v av[4][2], bv[2][2];                                                 \
    _Pragma("unroll")                                                           \
    for (int fm = 0; fm < 4; ++fm) {                                            \
      int row = (MH) * 128 + wr * 64 + fm * 16 + r16;                           \
      _Pragma("unroll")                                                         \
      for (int kk = 0; kk < 2; ++kk) {                                          \
        int kb = (kk * 64 + kg * 16) ^ ((row & 7) << 4);                        \
        av[fm][kk] = *(const short8v*)(la + row * 128 + kb);                    \
      }                                                                         \
    }                                                                           \
    _Pragma("unroll")                                                           \
    for (int fn = 0; fn < 2; ++fn) {                                            \
      int row = (NH) * 128 + wc * 32 + fn * 16 + r16;                           \
      _Pragma("unroll")                                                         \
      for (int kk = 0; kk < 2; ++kk) {                                          \
        int kb = (kk * 64 + kg * 16) ^ ((row & 7) << 4);                        \
        bv[fn][kk] = *(const short8v*)(lbp + row * 128 + kb);                   \
      }                                                                         \
    }                                                                           \
    __builtin_amdgcn_s_setprio(1);                                              \
    _Pragma("unroll")                                                           \
    for (int fm = 0; fm < 4; ++fm)                                              \
      _Pragma("unroll")                                                         \
      for (int fn = 0; fn < 2; ++fn)                                            \
        _Pragma("unroll")                                                       \
        for (int kk = 0; kk < 2; ++kk)                                          \
          acc[(MH) * 4 + fm][(NH) * 2 + fn] =                                   \
              __builtin_amdgcn_mfma_f32_16x16x32_bf16(                          \
                  av[fm][kk], bv[fn][kk],                                       \
                  acc[(MH) * 4 + fm][(NH) * 2 + fn], 0, 0, 0);                  \
    __builtin_amdgcn_s_setprio(0);                                              \
  }

__global__ __launch_bounds__(512, 2) void gemm256_kernel(
    const u16* __restrict__ A, const u16* __restrict__ Bt,
    const float* __restrict__ bias, const float* __restrict__ bfold,
    u16* __restrict__ Z, float* __restrict__ sum, float* __restrict__ sq,
    int M, int N, int Kp) {
  __shared__ char lds[131072];
  const int tid  = threadIdx.x;
  const int lane = tid & 63;
  const int wid  = tid >> 6;           // 0..7
  const int wr = wid >> 2, wc = wid & 3;  // 2M x 4N waves
  const int r16 = lane & 15, kg = lane >> 4;

  const int nmb = M >> 8;
  const int cpx = nmb >> 3;
  const int L   = blockIdx.x;
  const int xcd = L & 7;
  const int jj  = L >> 3;
  const int mb  = xcd * cpx + (jj % cpx);
  const int nb  = jj / cpx;
  const int m0  = mb * 256;
  const int n0  = nb * 256;
  const int ldb = Kp * 2;
  const int nt  = Kp >> 6;

  const char* gA = (const char*)A + (size_t)m0 * ldb;
  const char* gB = (const char*)Bt + (size_t)n0 * ldb;
  const int row0 = tid >> 3;
  const int kbs  = ((tid & 7) * 16) ^ ((row0 & 7) << 4);
  const size_t srcoff = (size_t)row0 * ldb + kbs;

  f32x4 acc[8][4];
  #pragma unroll
  for (int m = 0; m < 8; ++m)
    #pragma unroll
    for (int n = 0; n < 4; ++n) acc[m][n] = (f32x4){0.f, 0.f, 0.f, 0.f};

  STAGE(0, 0, 0); STAGE(1, 0, 0); STAGE(1, 1, 0); STAGE(0, 1, 0);
  STAGE(0, 0, 1); STAGE(1, 0, 1);
  BAR_VMN(8);

  const int Tmain = nt - 2;
  for (int T = 0; T < Tmain; ++T) {
    STAGE(1, 1, T + 1);
    PHASE(T, 0, 0);
    BAR_VMN(8);
    STAGE(0, 1, T + 1);
    PHASE(T, 0, 1);
    BAR_VMN(8);
    if (T + 2 < nt) STAGE(0, 0, T + 2);
    PHASE(T, 1, 0);
    BAR_NOVM();
    if (T + 2 < nt) STAGE(1, 0, T + 2);
    PHASE(T, 1, 1);
    BAR_VMN(8);
  }
  for (int T = Tmain; T < nt; ++T) {
    if (T + 1 < nt) STAGE(1, 1, T + 1);
    PHASE(T, 0, 0);
    BAR_VMN(0);
    if (T + 1 < nt) STAGE(0, 1, T + 1);
    PHASE(T, 0, 1);
    BAR_VMN(0);
    PHASE(T, 1, 0);
    BAR_NOVM();
    PHASE(T, 1, 1);
    BAR_VMN(0);
  }

  #pragma unroll
  for (int nh = 0; nh < 2; ++nh)
    #pragma unroll
    for (int fn = 0; fn < 2; ++fn) {
      int col = n0 + nh * 128 + wc * 32 + fn * 16 + r16;
      float bs = bias[col] + bfold[col];
      float ps = 0.f, pq = 0.f;
      #pragma unroll
      for (int mh = 0; mh < 2; ++mh)
        #pragma unroll
        for (int fm = 0; fm < 4; ++fm) {
          int rbase = m0 + mh * 128 + wr * 64 + fm * 16 + kg * 4;
          #pragma unroll
          for (int j2 = 0; j2 < 4; ++j2) {
            float val = acc[mh * 4 + fm][nh * 2 + fn][j2] + bs;
            Z[(size_t)(rbase + j2) * N + col] = f2b(val);
            ps += val; pq += val * val;
          }
        }
      ps += __shfl_xor(ps, 16, 64); ps += __shfl_xor(ps, 32, 64);
      pq += __shfl_xor(pq, 16, 64); pq += __shfl_xor(pq, 32, 64);
      if (lane < 16) {
        atomicAdd(&sum[col], ps);
        atomicAdd(&sq[col],  pq);
      }
    }
}

// ---------- 256x128-tile 8-wave 2-phase/K-tile pipelined GEMM (layer 2) ----------
#define STAGE2A(H, TILE)                                                        \
  {                                                                             \
    const char* sb = gA + (size_t)((H) * 128) * ldb + (size_t)(TILE) * 128 + srcoff; \
    char* db = lds + (((TILE) & 1) << 15) + ((H) << 14) + tid * 16;             \
    __builtin_amdgcn_global_load_lds((const AS1 unsigned*)sb,                   \
                                     (AS3 unsigned*)db, 16, 0, 0);              \
    __builtin_amdgcn_global_load_lds((const AS1 unsigned*)(sb + 64 * (size_t)ldb), \
                                     (AS3 unsigned*)(db + 8192), 16, 0, 0);     \
  }
#define STAGE2B(TILE)                                                           \
  {                                                                             \
    const char* sb = gB + (size_t)(TILE) * 128 + srcoff;                        \
    char* db = lds + 65536 + (((TILE) & 1) << 14) + tid * 16;                   \
    __builtin_amdgcn_global_load_lds((const AS1 unsigned*)sb,                   \
                                     (AS3 unsigned*)db, 16, 0, 0);              \
    __builtin_amdgcn_global_load_lds((const AS1 unsigned*)(sb + 64 * (size_t)ldb), \
                                     (AS3 unsigned*)(db + 8192), 16, 0, 0);     \
  }

#define PHASE2(T, MH)                                                           \
  {                                                                             \
    char* la  = lds + (((T) & 1) << 15) + ((MH) << 14);                         \
    char* lbp = lds + 65536 + (((T) & 1) << 14);                                \
    short8v av[4][2], bv[2][2];                                                 \
    _Pragma("unroll")                                                           \
    for (int fm = 0; fm < 4; ++fm) {                                            \
      int row = wr * 64 + fm * 16 + r16;                                        \
      _Pragma("unroll")                                                         \
      for (int kk = 0; kk < 2; ++kk) {                                          \
        int kb = (kk * 64 + kg * 16) ^ ((row & 7) << 4);                        \
        av[fm][kk] = *(const short8v*)(la + row * 128 + kb);                    \
      }                                                                         \
    }                                                                           \
    _Pragma("unroll")                                                           \
    for (int fn = 0; fn < 2; ++fn) {                                            \
      int row = wc * 32 + fn * 16 + r16;                                        \
      _Pragma("unroll")                                                         \
      for (int kk = 0; kk < 2; ++kk) {                                          \
        int kb = (kk * 64 + kg * 16) ^ ((row & 7) << 4);                        \
        bv[fn][kk] = *(const short8v*)(lbp + row * 128 + kb);                   \
      }                                                                         \
    }                                                                           \
    __builtin_amdgcn_s_setprio(1);                                              \
    _Pragma("unroll")                                                           \
    for (int fm = 0; fm < 4; ++fm)                                              \
      _Pragma("unroll")                                                         \
      for (int fn = 0; fn < 2; ++fn)                                            \
        _Pragma("unroll")                                                       \
        for (int kk = 0; kk < 2; ++kk)                                          \
          acc[(MH) * 4 + fm][fn] =                                              \
              __builtin_amdgcn_mfma_f32_16x16x32_bf16(                          \
                  av[fm][kk], bv[fn][kk], acc[(MH) * 4 + fm][fn], 0, 0, 0);     \
    __builtin_amdgcn_s_setprio(0);                                              \
  }

__global__ __launch_bounds__(512, 2) void gemm256x128_kernel(
    const u16* __restrict__ A, const u16* __restrict__ Bt,
    const float* __restrict__ bias, const float* __restrict__ bfold,
    u16* __restrict__ Z, float* __restrict__ sum, float* __restrict__ sq,
    int M, int N, int Kp) {
  __shared__ char lds[98304];
  const int tid  = threadIdx.x;
  const int lane = tid & 63;
  const int wid  = tid >> 6;              // 0..7
  const int wr = wid >> 2, wc = wid & 3;  // 2M x 4N
  const int r16 = lane & 15, kg = lane >> 4;

  const int nmb = M >> 8;                 // 64
  const int cpx = nmb >> 3;               // 8
  const int L   = blockIdx.x;
  const int xcd = L & 7;
  const int jj  = L >> 3;
  const int mb  = xcd * cpx + (jj % cpx);
  const int nb  = jj / cpx;
  const int m0  = mb * 256;
  const int n0  = nb * 128;
  const int ldb = Kp * 2;
  const int nt  = Kp >> 6;

  const char* gA = (const char*)A + (size_t)m0 * ldb;
  const char* gB = (const char*)Bt + (size_t)n0 * ldb;
  const int row0 = tid >> 3;
  const int kbs  = ((tid & 7) * 16) ^ ((row0 & 7) << 4);
  const size_t srcoff = (size_t)row0 * ldb + kbs;

  f32x4 acc[8][2];
  #pragma unroll
  for (int m = 0; m < 8; ++m)
    #pragma unroll
    for (int n = 0; n < 2; ++n) acc[m][n] = (f32x4){0.f, 0.f, 0.f, 0.f};

  STAGE2A(0, 0); STAGE2B(0); STAGE2A(1, 0);

  const int Tmain = nt - 1;
  for (int T = 0; T < Tmain; ++T) {
    STAGE2A(0, T + 1); STAGE2B(T + 1);   // 4 inst
    BAR_VMN(6);                          // proves A0,B(T)
    PHASE2(T, 0);
    STAGE2A(1, T + 1);                   // 2 inst
    BAR_VMN(6);                          // proves A1(T)
    PHASE2(T, 1);
    BAR_NOVM();
  }
  BAR_VMN(2);
  PHASE2(nt - 1, 0);
  BAR_VMN(0);
  PHASE2(nt - 1, 1);

  #pragma unroll
  for (int fn = 0; fn < 2; ++fn) {
    int col = n0 + wc * 32 + fn * 16 + r16;
    float bs = bias[col] + bfold[col];
    float ps = 0.f, pq = 0.f;
    #pragma unroll
    for (int mh = 0; mh < 2; ++mh)
      #pragma unroll
      for (int fm = 0; fm < 4; ++fm) {
        int rbase = m0 + mh * 128 + wr * 64 + fm * 16 + kg * 4;
        #pragma unroll
        for (int j2 = 0; j2 < 4; ++j2) {
          float val = acc[mh * 4 + fm][fn][j2] + bs;
          Z[(size_t)(rbase + j2) * N + col] = f2b(val);
          ps += val; pq += val * val;
        }
      }
    ps += __shfl_xor(ps, 16, 64); ps += __shfl_xor(ps, 32, 64);
    pq += __shfl_xor(pq, 16, 64); pq += __shfl_xor(pq, 32, 64);
    if (lane < 16) {
      atomicAdd(&sum[col], ps);
      atomicAdd(&sq[col],  pq);
    }
  }
}

// ---------- final: BN3 inline from stats + concat-dot + sigmoid (float32 out) ----------
__global__ void final_kernel(const u16* __restrict__ z3, const float* __restrict__ sum3,
                             const float* __restrict__ sq3, const float* __restrict__ g3,
                             const float* __restrict__ b3, float invM,
                             const float* __restrict__ Wp, const float* __restrict__ bp,
                             const float* __restrict__ crossc, float* __restrict__ out) {
  int wv = threadIdx.x >> 6, lane = threadIdx.x & 63;
  int b = blockIdx.x * 4 + wv;
  const float* wph = Wp + kInDim;
  float s = 0.f;
  #pragma unroll
  for (int k = lane; k < kH3; k += 64) {
    float mu  = sum3[k] * invM;
    float var = sq3[k] * invM - mu * mu;
    float a   = g3[k] * rsqrtf(var + kEps);
    float cc  = b3[k] - a * mu;
    float h = a * b2f(z3[(size_t)b * kH3 + k]) + cc;
    s += h * wph[k];
  }
  #pragma unroll
  for (int off = 32; off; off >>= 1) s += __shfl_down(s, off, 64);
  if (lane == 0) {
    float logit = s + crossc[b] + bp[0];
    out[b] = 1.f / (1.f + expf(-logit));
  }
}

// ---------- workspace layout ----------
constexpr size_t OFF_X0    = 0;                                   // 16384*1728*2
constexpr size_t OFF_Z1    = OFF_X0 + (size_t)kBatch * kInPad * 2;
constexpr size_t OFF_Z2    = OFF_Z1 + (size_t)kBatch * kH1 * 2;
constexpr size_t OFF_Z3    = OFF_Z2 + (size_t)kBatch * kH2 * 2;
constexpr size_t OFF_W1T   = OFF_Z3 + (size_t)kBatch * kH3 * 2;
constexpr size_t OFF_W2T   = OFF_W1T + (size_t)kH1 * kInPad * 2;
constexpr size_t OFF_W3T   = OFF_W2T + (size_t)kH2 * kH1 * 2;
constexpr size_t OFF_CROSS = OFF_W3T + (size_t)kH3 * kH2 * 2;
constexpr size_t OFF_STATS = OFF_CROSS + (size_t)kBatch * 4;
constexpr size_t OFF_BF    = OFF_STATS + (size_t)kStatsFloats * 4;
// total ~115 MB

extern "C" void kernel_launch(void* const* d_in, const int* in_sizes, int n_in,
                              void* d_out, int out_size, void* d_ws, size_t ws_size,
                              hipStream_t stream) {
  const int*   sparse  = (const int*)d_in[0];
  const float* dense   = (const float*)d_in[1];
  const float* emb     = (const float*)d_in[2];
  const float* w_cross = (const float*)d_in[3];
  const float* b_cross = (const float*)d_in[4];
  const float* bn0_g = (const float*)d_in[5],  *bn0_b = (const float*)d_in[6];
  const float* W1    = (const float*)d_in[7],  *bias1 = (const float*)d_in[8];
  const float* bn1_g = (const float*)d_in[9],  *bn1_b = (const float*)d_in[10];
  const float* W2    = (const float*)d_in[11], *bias2 = (const float*)d_in[12];
  const float* bn2_g = (const float*)d_in[13], *bn2_b = (const float*)d_in[14];
  const float* W3    = (const float*)d_in[15], *bias3 = (const float*)d_in[16];
  const float* bn3_g = (const float*)d_in[17], *bn3_b = (const float*)d_in[18];
  const float* Wp    = (const float*)d_in[19], *bp    = (const float*)d_in[20];

  char* ws = (char*)d_ws;
  u16* x0  = (u16*)(ws + OFF_X0);
  u16* z1  = (u16*)(ws + OFF_Z1);
  u16* z2  = (u16*)(ws + OFF_Z2);
  u16* z3  = (u16*)(ws + OFF_Z3);
  u16* W1t = (u16*)(ws + OFF_W1T);
  u16* W2t = (u16*)(ws + OFF_W2T);
  u16* W3t = (u16*)(ws + OFF_W3T);
  float* crossc = (float*)(ws + OFF_CROSS);
  float* stats  = (float*)(ws + OFF_STATS);
  float* sum0 = stats,            *sq0 = stats + kInPad;
  float* sum1 = sq0 + kInPad,     *sq1 = sum1 + kH1;
  float* sum2 = sq1 + kH1,        *sq2 = sum2 + kH2;
  float* sum3 = sq2 + kH2,        *sq3 = sum3 + kH3;
  float* bfold = (float*)(ws + OFF_BF);
  float* b1f = bfold, *b2f = b1f + kH1, *b3f = b2f + kH2;
  float* out = (float*)d_out;

  const float invM = 1.f / (float)kBatch;

  // gather also zeroes stats (block 0) and computes per-block sum(Wp) locally
  gather_kernel<<<kBatch, 256, 0, stream>>>(sparse, dense, emb, w_cross, b_cross, Wp,
                                            x0, crossc, stats);

  // BN0 stats -> fold into W1/bias1
  colstats_kernel<<<dim3(kInPad / 64, kBatch / 512), 256, 0, stream>>>(x0, kInPad, sum0, sq0);
  fold_kernel<<<dim3(kInPad / 64, kH1 / 64), 256, 0, stream>>>(
      W1, sum0, sq0, bn0_g, bn0_b, invM, W1t, b1f, kInDim, kH1, kInPad);

  // layer 1: 256x256 pipelined GEMM (stats fused)
  gemm256_kernel<<<(kBatch / 256) * (kH1 / 256), 512, 0, stream>>>(
      x0, W1t, bias1, b1f, z1, sum1, sq1, kBatch, kH1, kInPad);
  fold_kernel<<<dim3(kH1 / 64, kH2 / 64), 256, 0, stream>>>(
      W2, sum1, sq1, bn1_g, bn1_b, invM, W2t, b2f, kH1, kH2, kH1);

  // layer 2: 256x128 pipelined GEMM (stats fused)
  gemm256x128_kernel<<<(kBatch / 256) * (kH2 / 128), 512, 0, stream>>>(
      z1, W2t, bias2, b2f, z2, sum2, sq2, kBatch, kH2, kH1);
  fold_kernel<<<dim3(kH2 / 64, kH3 / 64), 256, 0, stream>>>(
      W3, sum2, sq2, bn2_g, bn2_b, invM, W3t, b3f, kH2, kH3, kH2);

  // layer 3: 128x128 pipelined GEMM (BN3 inline in final)
  gemm_kernel<<<dim3(kH3 / 128, kBatch / 128), 256, 0, stream>>>(
      z2, W3t, bias3, b3f, z3, sum3, sq3, kBatch, kH3, kH2);

  final_kernel<<<kBatch / 4, 256, 0, stream>>>(z3, sum3, sq3, bn3_g, bn3_b, invM,
                                               Wp, bp, crossc, out);
}